// Round 15
// baseline (976.498 us; speedup 1.0000x reference)
//
#include <hip/hip_runtime.h>
#include <math.h>

#define BB 4
#define LL 1024
#define DD 1024
#define KK 20
#define CC 21
#define LC (LL * CC)          // 21504 floats per (b, i) output row-panel
#define NQ (LC / 4)           // 5376 float4 per panel

typedef float vf4    __attribute__((ext_vector_type(4)));
typedef short bf16x8 __attribute__((ext_vector_type(8)));  // MFMA A/B frag (8 bf16)
typedef float f32x4  __attribute__((ext_vector_type(4)));  // MFMA C/D frag

__device__ __forceinline__ unsigned short f2bf(float f) {  // RNE f32->bf16
    unsigned int u = __builtin_bit_cast(unsigned int, f);
    u += 0x7FFFu + ((u >> 16) & 1u);
    return (unsigned short)(u >> 16);
}

// fire-and-forget 16B/lane global->LDS DMA (wave-uniform LDS base + lane*16)
__device__ __forceinline__ void gload_lds16(const float* g, float* l) {
    __builtin_amdgcn_global_load_lds(
        (const __attribute__((address_space(1))) unsigned int*)g,
        (__attribute__((address_space(3))) unsigned int*)l, 16, 0, 0);
}

__device__ __forceinline__ float wave_reduce_sum(float v) {
    #pragma unroll
    for (int off = 1; off < 64; off <<= 1)
        v += __shfl_xor(v, off, 64);
    return v;
}

#define DOT4(a, b) ((a).x*(b).x + (a).y*(b).y + (a).z*(b).z + (a).w*(b).w)

// ---------------------------------------------------------------------------
// Kernel 0 (DIAGNOSTIC rep): zd/M dots + Wcat build, repeated `rep` times.
// ---------------------------------------------------------------------------
__global__ __launch_bounds__(64) void k0_zdM(
    const float* __restrict__ dic,
    const float* __restrict__ Wz_w, const float* __restrict__ Wz_b,
    const float* __restrict__ cs_w, const float* __restrict__ Wy_w,
    float* __restrict__ zd, float* __restrict__ M,
    unsigned short* __restrict__ Wcat, int rep)
{
    int blk = blockIdx.x;
    int lane = threadIdx.x;

    for (int rp = 0; rp < rep; ++rp) {
        asm volatile("" ::: "memory");
        if (blk < 2 * KK * CC) {
            bool isM = (blk >= KK * CC);
            int e2 = isM ? blk - KK * CC : blk;
            int k = e2 / CC, c = e2 % CC;
            const float4* a4 = reinterpret_cast<const float4*>(dic + (size_t)k * DD);
            const float*  w  = isM ? (cs_w + (size_t)c * (2 * DD) + DD) : (Wz_w + (size_t)c * DD);
            const float4* w4 = reinterpret_cast<const float4*>(w);
            float p = 0.f;
            #pragma unroll
            for (int i = 0; i < 4; ++i) {
                float4 av = a4[lane + 64 * i];
                float4 wv = w4[lane + 64 * i];
                p += DOT4(av, wv);
            }
            p = wave_reduce_sum(p);
            if (lane == 0) {
                if (isM) M[e2] = p;
                else     zd[e2] = p + Wz_b[c];
            }
        } else {
            int e2 = blk - 2 * KK * CC;       // 0..23, each converts 2048 elems
            int base = e2 * 2048;
            #pragma unroll
            for (int t = 0; t < 32; ++t) {
                int i = base + lane + 64 * t;
                int c = i >> 10, k = i & 1023;
                float v;
                if (c < CC)          v = Wy_w[(size_t)c * DD + k];
                else if (c < 2 * CC) v = cs_w[(size_t)(c - CC) * (2 * DD) + k];
                else                 v = 0.f;
                Wcat[i] = f2bf(v);
            }
        }
    }
}

// ---------------------------------------------------------------------------
// Kernel 1 v7 (DIAGNOSTIC rep): full body incl. gload_lds staging per rep.
// ---------------------------------------------------------------------------
__global__ __launch_bounds__(512) void k1_mfma(
    const float* __restrict__ x,
    const float* __restrict__ prior,
    const float* __restrict__ Wy_b, const float* __restrict__ cs_b,
    const unsigned short* __restrict__ Wcat,
    const float* __restrict__ zd, const float* __restrict__ M,
    float* __restrict__ ly_ws, float* __restrict__ lz_ws, int rep)
{
    const int tid  = threadIdx.x;
    const int wid  = tid >> 6;          // 0..7
    const int lane = tid & 63;
    const int fr   = lane & 15;
    const int kg   = lane >> 4;
    const int r0   = blockIdx.x * 16;

    __shared__ float zds[KK * CC];
    __shared__ float Ms[KK * CC];
    __shared__ float pr[KK];
    __shared__ float bias[2 * CC];
    __shared__ float xT[16 * 1024];     // 64 KB, LINEAR (gload_lds requirement)
    __shared__ float pacc[8 * 16 * 49];

    for (int i = tid; i < KK * CC; i += 512) { zds[i] = zd[i]; Ms[i] = M[i]; }
    if (tid < KK) pr[tid] = prior[tid];
    if (tid < CC) { bias[tid] = Wy_b[tid]; bias[CC + tid] = cs_b[tid]; }
    __syncthreads();

    for (int rp = 0; rp < rep; ++rp) {
        asm volatile("" ::: "memory");

        // ---- stage x-tile: 8 fire-and-forget 1KB wave-DMAs per wave ----
        {
            const float* gbase = x + (size_t)r0 * DD;
            #pragma unroll
            for (int i = 0; i < 8; ++i) {
                int chunk = wid * 8 + i;
                gload_lds16(gbase + chunk * 256 + lane * 4, &xT[chunk * 256]);
            }
        }
        __syncthreads();                    // drains vmcnt + lds

        const int kbase = wid * 128;
        const unsigned short* w0p = Wcat + (size_t)(fr +  0) * DD + kbase + kg * 8;
        const unsigned short* w1p = Wcat + (size_t)(fr + 16) * DD + kbase + kg * 8;
        const unsigned short* w2p = Wcat + (size_t)(fr + 32) * DD + kbase + kg * 8;
        const float*          ap  = &xT[fr * 1024 + kbase + kg * 8];

        f32x4 acc0 = {0.f, 0.f, 0.f, 0.f};
        f32x4 acc1 = {0.f, 0.f, 0.f, 0.f};
        f32x4 acc2 = {0.f, 0.f, 0.f, 0.f};

        #pragma unroll
        for (int ks = 0; ks < 4; ++ks) {
            float4 a0 = *reinterpret_cast<const float4*>(ap + ks * 32);
            float4 a1 = *reinterpret_cast<const float4*>(ap + ks * 32 + 4);
            bf16x8 af;
            af[0] = (short)f2bf(a0.x); af[1] = (short)f2bf(a0.y);
            af[2] = (short)f2bf(a0.z); af[3] = (short)f2bf(a0.w);
            af[4] = (short)f2bf(a1.x); af[5] = (short)f2bf(a1.y);
            af[6] = (short)f2bf(a1.z); af[7] = (short)f2bf(a1.w);
            bf16x8 b0 = *reinterpret_cast<const bf16x8*>(w0p + ks * 32);
            bf16x8 b1 = *reinterpret_cast<const bf16x8*>(w1p + ks * 32);
            bf16x8 b2 = *reinterpret_cast<const bf16x8*>(w2p + ks * 32);
            acc0 = __builtin_amdgcn_mfma_f32_16x16x32_bf16(af, b0, acc0, 0, 0, 0);
            acc1 = __builtin_amdgcn_mfma_f32_16x16x32_bf16(af, b1, acc1, 0, 0, 0);
            acc2 = __builtin_amdgcn_mfma_f32_16x16x32_bf16(af, b2, acc2, 0, 0, 0);
        }

        #pragma unroll
        for (int j = 0; j < 4; ++j) {
            float* pw = pacc + ((wid * 16) + kg * 4 + j) * 49;
            pw[fr]      = acc0[j];
            pw[16 + fr] = acc1[j];
            pw[32 + fr] = acc2[j];
        }
        __syncthreads();

        #pragma unroll
        for (int p = 0; p < 2; ++p) {
            int o = tid + p * 512;
            if (o < 768) {
                int row = o / 48, col = o % 48;
                float s = 0.f;
                #pragma unroll
                for (int w = 0; w < 8; ++w) s += pacc[((w * 16) + row) * 49 + col];
                pacc[row * 49 + col] = s;
            }
        }
        __syncthreads();

        if (tid < 64) {
            const float* f = pacc + fr * 49;
            const float scale = 0.21821789023599238f;   // 1/sqrt(21)
            float s[KK];
            float m = -1e30f;
            #pragma unroll
            for (int k = 0; k < KK; ++k) {
                float t = 0.f;
                #pragma unroll
                for (int c = 0; c < CC; ++c) t += (f[c] + bias[c]) * zds[k * CC + c];
                s[k] = t * scale;
                m = fmaxf(m, s[k]);
            }
            float sum = 0.f;
            #pragma unroll
            for (int k = 0; k < KK; ++k) { s[k] = expf(s[k] - m); sum += s[k]; }
            float inv = 1.f / sum;
            float wk[KK];
            #pragma unroll
            for (int k = 0; k < KK; ++k) wk[k] = s[k] * inv * pr[k];

            size_t rr = (size_t)(r0 + fr);
            for (int c = kg; c < CC; c += 4) {
                float lzv = bias[CC + c];                   // cs_b
                #pragma unroll
                for (int k = 0; k < KK; ++k) lzv += wk[k] * Ms[k * CC + c];
                ly_ws[rr * CC + c] = f[CC + c];
                lz_ws[rr * CC + c] = lzv;
            }
        }
        __syncthreads();                // protect xT/pacc WAR vs next rep
    }
}

// ---------------------------------------------------------------------------
// Kernel 2 (DIAGNOSTIC rep): 512-thr pattern-table, regular stores.
// ---------------------------------------------------------------------------
__global__ __launch_bounds__(512) void k2_outer(
    const float* __restrict__ ly_ws, const float* __restrict__ lz_ws,
    float* __restrict__ out, int rep)
{
    int tid = threadIdx.x;
    int blk = blockIdx.x;               // 0..1023
    int b  = blk >> 8;                  // 256 blocks per image
    int i0 = (blk & 255) << 2;          // * 4 panels

    __shared__ vf4 lyp4[4 * CC];
    {
        float* lyp = reinterpret_cast<float*>(lyp4);
        if (tid < 4 * 84) {
            int i = tid / 84, f = tid % 84;
            lyp[i * 84 + f] = ly_ws[(size_t)(b * LL + i0 + i) * CC + (f % 21)];
        }
    }
    const float* lzp = lz_ws + (size_t)b * LC;
    vf4 lzv[11];
    #pragma unroll
    for (int it = 0; it < 11; ++it) {
        int idx = tid + it * 512;
        lzv[it] = (idx < NQ) ? *reinterpret_cast<const vf4*>(lzp + (size_t)idx * 4)
                             : (vf4){0.f, 0.f, 0.f, 0.f};
    }
    __syncthreads();
    int g0 = tid % 21;                  // (tid + it*512) % 21 steps by +8 mod 21

    for (int rp = 0; rp < rep; ++rp) {
        asm volatile("" ::: "memory");
        #pragma unroll
        for (int i = 0; i < 4; ++i) {
            float* op = out + (size_t)(b * LL + i0 + i) * LC;
            const vf4* lyp_i = lyp4 + i * CC;
            int g = g0;
            #pragma unroll
            for (int it = 0; it < 11; ++it) {
                int idx = tid + it * 512;
                if (idx < NQ) {
                    *reinterpret_cast<vf4*>(op + (size_t)idx * 4) = lzv[it] + lyp_i[g];
                }
                g += 8; if (g >= 21) g -= 21;
            }
        }
    }
}

extern "C" void kernel_launch(void* const* d_in, const int* in_sizes, int n_in,
                              void* d_out, int out_size, void* d_ws, size_t ws_size,
                              hipStream_t stream)
{
    const float* x     = (const float*)d_in[0];
    const float* dic   = (const float*)d_in[1];
    const float* prior = (const float*)d_in[2];
    const float* Wy_w  = (const float*)d_in[3];
    const float* Wy_b  = (const float*)d_in[4];
    const float* Wz_w  = (const float*)d_in[5];
    const float* Wz_b  = (const float*)d_in[6];
    const float* cs_w  = (const float*)d_in[7];
    const float* cs_b  = (const float*)d_in[8];
    float* out = (float*)d_out;

    float* ws = (float*)d_ws;
    float* zd = ws;                       // 420 floats
    float* M  = ws + 512;                 // 420 floats
    float* ly = ws + 1024;                // B*L*C = 86016 floats
    float* lz = ly + BB * LL * CC;        // 86016 floats
    unsigned short* Wcat = (unsigned short*)(ws + 1024 + 2 * BB * LL * CC);  // 48*1024 bf16

    k0_zdM <<<dim3(2 * KK * CC + 24), dim3(64),  0, stream>>>(dic, Wz_w, Wz_b, cs_w, Wy_w,
                                                              zd, M, Wcat, 30);
    k1_mfma<<<dim3(BB * LL / 16),     dim3(512), 0, stream>>>(x, prior, Wy_b, cs_b, Wcat,
                                                              zd, M, ly, lz, 50);
    k2_outer<<<dim3(BB * LL / 4),     dim3(512), 0, stream>>>(ly, lz, out, 5);
}

// Round 16
// 482.255 us; speedup vs baseline: 2.0249x; 2.0249x over previous
//
#include <hip/hip_runtime.h>
#include <math.h>

#define BB 4
#define LL 1024
#define DD 1024
#define KK 20
#define CC 21
#define LC (LL * CC)          // 21504 floats per (b, i) output row-panel
#define NQ (LC / 4)           // 5376 float4 per panel

typedef float vf4    __attribute__((ext_vector_type(4)));
typedef short bf16x8 __attribute__((ext_vector_type(8)));  // MFMA A/B frag (8 bf16)
typedef float f32x4  __attribute__((ext_vector_type(4)));  // MFMA C/D frag

__device__ __forceinline__ unsigned short f2bf(float f) {  // RNE f32->bf16
    unsigned int u = __builtin_bit_cast(unsigned int, f);
    u += 0x7FFFu + ((u >> 16) & 1u);
    return (unsigned short)(u >> 16);
}

// fire-and-forget 16B/lane global->LDS DMA (wave-uniform LDS base + lane*16)
__device__ __forceinline__ void gload_lds16(const float* g, float* l) {
    __builtin_amdgcn_global_load_lds(
        (const __attribute__((address_space(1))) unsigned int*)g,
        (__attribute__((address_space(3))) unsigned int*)l, 16, 0, 0);
}

__device__ __forceinline__ float wave_reduce_sum(float v) {
    #pragma unroll
    for (int off = 1; off < 64; off <<= 1)
        v += __shfl_xor(v, off, 64);
    return v;
}

#define DOT4(a, b) ((a).x*(b).x + (a).y*(b).y + (a).z*(b).z + (a).w*(b).w)

// ---------------------------------------------------------------------------
// Kernel 0: zd/M dots (float4) + Wcat bf16 build. Measured ~2.6 us warm.
// ---------------------------------------------------------------------------
__global__ __launch_bounds__(64) void k0_zdM(
    const float* __restrict__ dic,
    const float* __restrict__ Wz_w, const float* __restrict__ Wz_b,
    const float* __restrict__ cs_w, const float* __restrict__ Wy_w,
    float* __restrict__ zd, float* __restrict__ M,
    unsigned short* __restrict__ Wcat)
{
    int blk = blockIdx.x;
    int lane = threadIdx.x;

    if (blk < 2 * KK * CC) {
        bool isM = (blk >= KK * CC);
        int e2 = isM ? blk - KK * CC : blk;
        int k = e2 / CC, c = e2 % CC;
        const float4* a4 = reinterpret_cast<const float4*>(dic + (size_t)k * DD);
        const float*  w  = isM ? (cs_w + (size_t)c * (2 * DD) + DD) : (Wz_w + (size_t)c * DD);
        const float4* w4 = reinterpret_cast<const float4*>(w);
        float p = 0.f;
        #pragma unroll
        for (int i = 0; i < 4; ++i) {
            float4 av = a4[lane + 64 * i];
            float4 wv = w4[lane + 64 * i];
            p += DOT4(av, wv);
        }
        p = wave_reduce_sum(p);
        if (lane == 0) {
            if (isM) M[e2] = p;
            else     zd[e2] = p + Wz_b[c];
        }
    } else {
        int e2 = blk - 2 * KK * CC;       // 0..23, each converts 2048 elems
        int base = e2 * 2048;
        #pragma unroll
        for (int t = 0; t < 32; ++t) {
            int i = base + lane + 64 * t;
            int c = i >> 10, k = i & 1023;
            float v;
            if (c < CC)          v = Wy_w[(size_t)c * DD + k];
            else if (c < 2 * CC) v = cs_w[(size_t)(c - CC) * (2 * DD) + k];
            else                 v = 0.f;
            Wcat[i] = f2bf(v);
        }
    }
}

// ---------------------------------------------------------------------------
// Kernel 1 v7 + DIAGNOSTIC SLEEP TAIL: real work once (in-situ conditions
// preserved), then ~203 us of s_sleep so the dispatch surfaces in top-5.
// In-situ k1 cost = dur_us - 203. 256 blocks = 1/CU -> single pass.
// ---------------------------------------------------------------------------
__global__ __launch_bounds__(512) void k1_mfma(
    const float* __restrict__ x,
    const float* __restrict__ prior,
    const float* __restrict__ Wy_b, const float* __restrict__ cs_b,
    const unsigned short* __restrict__ Wcat,
    const float* __restrict__ zd, const float* __restrict__ M,
    float* __restrict__ ly_ws, float* __restrict__ lz_ws, int sleep_iters)
{
    const int tid  = threadIdx.x;
    const int wid  = tid >> 6;          // 0..7
    const int lane = tid & 63;
    const int fr   = lane & 15;
    const int kg   = lane >> 4;
    const int r0   = blockIdx.x * 16;

    __shared__ float zds[KK * CC];
    __shared__ float Ms[KK * CC];
    __shared__ float pr[KK];
    __shared__ float bias[2 * CC];
    __shared__ float xT[16 * 1024];     // 64 KB, LINEAR (gload_lds requirement)
    __shared__ float pacc[8 * 16 * 49];

    // ---- stage x-tile: 8 fire-and-forget 1KB wave-DMAs per wave ----
    {
        const float* gbase = x + (size_t)r0 * DD;       // 16 rows contiguous
        #pragma unroll
        for (int i = 0; i < 8; ++i) {
            int chunk = wid * 8 + i;                    // 0..63, 256 floats each
            gload_lds16(gbase + chunk * 256 + lane * 4, &xT[chunk * 256]);
        }
    }

    for (int i = tid; i < KK * CC; i += 512) { zds[i] = zd[i]; Ms[i] = M[i]; }
    if (tid < KK) pr[tid] = prior[tid];
    if (tid < CC) { bias[tid] = Wy_b[tid]; bias[CC + tid] = cs_b[tid]; }
    __syncthreads();                    // drains vmcnt (gload_lds) + lds

    // ---- MFMA over this wave's K-slice ----
    const int kbase = wid * 128;
    const unsigned short* w0p = Wcat + (size_t)(fr +  0) * DD + kbase + kg * 8;
    const unsigned short* w1p = Wcat + (size_t)(fr + 16) * DD + kbase + kg * 8;
    const unsigned short* w2p = Wcat + (size_t)(fr + 32) * DD + kbase + kg * 8;
    const float*          ap  = &xT[fr * 1024 + kbase + kg * 8];

    f32x4 acc0 = {0.f, 0.f, 0.f, 0.f};
    f32x4 acc1 = {0.f, 0.f, 0.f, 0.f};
    f32x4 acc2 = {0.f, 0.f, 0.f, 0.f};

    #pragma unroll
    for (int ks = 0; ks < 4; ++ks) {
        float4 a0 = *reinterpret_cast<const float4*>(ap + ks * 32);
        float4 a1 = *reinterpret_cast<const float4*>(ap + ks * 32 + 4);
        bf16x8 af;
        af[0] = (short)f2bf(a0.x); af[1] = (short)f2bf(a0.y);
        af[2] = (short)f2bf(a0.z); af[3] = (short)f2bf(a0.w);
        af[4] = (short)f2bf(a1.x); af[5] = (short)f2bf(a1.y);
        af[6] = (short)f2bf(a1.z); af[7] = (short)f2bf(a1.w);
        bf16x8 b0 = *reinterpret_cast<const bf16x8*>(w0p + ks * 32);
        bf16x8 b1 = *reinterpret_cast<const bf16x8*>(w1p + ks * 32);
        bf16x8 b2 = *reinterpret_cast<const bf16x8*>(w2p + ks * 32);
        acc0 = __builtin_amdgcn_mfma_f32_16x16x32_bf16(af, b0, acc0, 0, 0, 0);
        acc1 = __builtin_amdgcn_mfma_f32_16x16x32_bf16(af, b1, acc1, 0, 0, 0);
        acc2 = __builtin_amdgcn_mfma_f32_16x16x32_bf16(af, b2, acc2, 0, 0, 0);
    }

    // D frags -> pacc[wid]: m = kg*4+j (x-row), cols fr / 16+fr / 32+fr
    #pragma unroll
    for (int j = 0; j < 4; ++j) {
        float* pw = pacc + ((wid * 16) + kg * 4 + j) * 49;
        pw[fr]      = acc0[j];
        pw[16 + fr] = acc1[j];
        pw[32 + fr] = acc2[j];
    }
    __syncthreads();

    // cross-wave reduce: 768 outputs, 8-way, thread-owned in-place into w=0
    #pragma unroll
    for (int p = 0; p < 2; ++p) {
        int o = tid + p * 512;
        if (o < 768) {
            int row = o / 48, col = o % 48;
            float s = 0.f;
            #pragma unroll
            for (int w = 0; w < 8; ++w) s += pacc[((w * 16) + row) * 49 + col];
            pacc[row * 49 + col] = s;
        }
    }
    __syncthreads();

    // wave-0 epilogue: softmax for row fr (4-way redundant over kg), lz c=kg::4
    if (tid < 64) {
        const float* f = pacc + fr * 49;
        const float scale = 0.21821789023599238f;   // 1/sqrt(21)
        float s[KK];
        float m = -1e30f;
        #pragma unroll
        for (int k = 0; k < KK; ++k) {
            float t = 0.f;
            #pragma unroll
            for (int c = 0; c < CC; ++c) t += (f[c] + bias[c]) * zds[k * CC + c];
            s[k] = t * scale;
            m = fmaxf(m, s[k]);
        }
        float sum = 0.f;
        #pragma unroll
        for (int k = 0; k < KK; ++k) { s[k] = expf(s[k] - m); sum += s[k]; }
        float inv = 1.f / sum;
        float wk[KK];
        #pragma unroll
        for (int k = 0; k < KK; ++k) wk[k] = s[k] * inv * pr[k];

        size_t rr = (size_t)(r0 + fr);
        for (int c = kg; c < CC; c += 4) {
            float lzv = bias[CC + c];                   // cs_b
            #pragma unroll
            for (int k = 0; k < KK; ++k) lzv += wk[k] * Ms[k * CC + c];
            ly_ws[rr * CC + c] = f[CC + c];             // cols 21..41 = ly
            lz_ws[rr * CC + c] = lzv;
        }
    }

    // ---- diagnostic sleep tail: ~3.39 us per iter at 2.4 GHz ----
    for (int i = 0; i < sleep_iters; ++i) __builtin_amdgcn_s_sleep(127);
}

// ---------------------------------------------------------------------------
// Kernel 2 (DIAGNOSTIC rep x5): 512-thr pattern-table, regular stores.
// Write-dominated => every rep ~= in-situ cost; dur/5 = per-invocation.
// ---------------------------------------------------------------------------
__global__ __launch_bounds__(512) void k2_outer(
    const float* __restrict__ ly_ws, const float* __restrict__ lz_ws,
    float* __restrict__ out, int rep)
{
    int tid = threadIdx.x;
    int blk = blockIdx.x;               // 0..1023
    int b  = blk >> 8;                  // 256 blocks per image
    int i0 = (blk & 255) << 2;          // * 4 panels

    __shared__ vf4 lyp4[4 * CC];
    {
        float* lyp = reinterpret_cast<float*>(lyp4);
        if (tid < 4 * 84) {
            int i = tid / 84, f = tid % 84;
            lyp[i * 84 + f] = ly_ws[(size_t)(b * LL + i0 + i) * CC + (f % 21)];
        }
    }
    const float* lzp = lz_ws + (size_t)b * LC;
    vf4 lzv[11];
    #pragma unroll
    for (int it = 0; it < 11; ++it) {
        int idx = tid + it * 512;
        lzv[it] = (idx < NQ) ? *reinterpret_cast<const vf4*>(lzp + (size_t)idx * 4)
                             : (vf4){0.f, 0.f, 0.f, 0.f};
    }
    __syncthreads();
    int g0 = tid % 21;                  // (tid + it*512) % 21 steps by +8 mod 21

    for (int rp = 0; rp < rep; ++rp) {
        asm volatile("" ::: "memory");
        #pragma unroll
        for (int i = 0; i < 4; ++i) {
            float* op = out + (size_t)(b * LL + i0 + i) * LC;
            const vf4* lyp_i = lyp4 + i * CC;
            int g = g0;
            #pragma unroll
            for (int it = 0; it < 11; ++it) {
                int idx = tid + it * 512;
                if (idx < NQ) {
                    *reinterpret_cast<vf4*>(op + (size_t)idx * 4) = lzv[it] + lyp_i[g];
                }
                g += 8; if (g >= 21) g -= 21;
            }
        }
    }
}

extern "C" void kernel_launch(void* const* d_in, const int* in_sizes, int n_in,
                              void* d_out, int out_size, void* d_ws, size_t ws_size,
                              hipStream_t stream)
{
    const float* x     = (const float*)d_in[0];
    const float* dic   = (const float*)d_in[1];
    const float* prior = (const float*)d_in[2];
    const float* Wy_w  = (const float*)d_in[3];
    const float* Wy_b  = (const float*)d_in[4];
    const float* Wz_w  = (const float*)d_in[5];
    const float* Wz_b  = (const float*)d_in[6];
    const float* cs_w  = (const float*)d_in[7];
    const float* cs_b  = (const float*)d_in[8];
    float* out = (float*)d_out;

    float* ws = (float*)d_ws;
    float* zd = ws;                       // 420 floats
    float* M  = ws + 512;                 // 420 floats
    float* ly = ws + 1024;                // B*L*C = 86016 floats
    float* lz = ly + BB * LL * CC;        // 86016 floats
    unsigned short* Wcat = (unsigned short*)(ws + 1024 + 2 * BB * LL * CC);  // 48*1024 bf16

    k0_zdM <<<dim3(2 * KK * CC + 24), dim3(64),  0, stream>>>(dic, Wz_w, Wz_b, cs_w, Wy_w,
                                                              zd, M, Wcat);
    k1_mfma<<<dim3(BB * LL / 16),     dim3(512), 0, stream>>>(x, prior, Wy_b, cs_b, Wcat,
                                                              zd, M, ly, lz, 60);
    k2_outer<<<dim3(BB * LL / 4),     dim3(512), 0, stream>>>(ly, lz, out, 5);
}

// Round 18
// 101.523 us; speedup vs baseline: 9.6185x; 4.7502x over previous
//
#include <hip/hip_runtime.h>
#include <math.h>

#define BB 4
#define LL 1024
#define DD 1024
#define KK 20
#define CC 21
#define LC (LL * CC)          // 21504 floats per (b, i) output row-panel
#define NQ (LC / 4)           // 5376 float4 per panel
#define XS 1032               // xT row stride in bf16 elems (1024 + 8 pad)

typedef float vf4    __attribute__((ext_vector_type(4)));
typedef short bf16x8 __attribute__((ext_vector_type(8)));  // MFMA A/B frag (8 bf16)
typedef float f32x4  __attribute__((ext_vector_type(4)));  // MFMA C/D frag

__device__ __forceinline__ unsigned short f2bf(float f) {  // RNE f32->bf16
    unsigned int u = __builtin_bit_cast(unsigned int, f);
    u += 0x7FFFu + ((u >> 16) & 1u);
    return (unsigned short)(u >> 16);
}

__device__ __forceinline__ float wave_reduce_sum(float v) {
    #pragma unroll
    for (int off = 1; off < 64; off <<= 1)
        v += __shfl_xor(v, off, 64);
    return v;
}

#define DOT4(a, b) ((a).x*(b).x + (a).y*(b).y + (a).z*(b).z + (a).w*(b).w)

// ---------------------------------------------------------------------------
// Kernel 0: blocks 0..839: zd[k,c], M[k,c] (float4 dots);
//           blocks 840..863: Wcat bf16 [48][1024]. Measured ~2.6 us.
// ---------------------------------------------------------------------------
__global__ __launch_bounds__(64) void k0_zdM(
    const float* __restrict__ dic,
    const float* __restrict__ Wz_w, const float* __restrict__ Wz_b,
    const float* __restrict__ cs_w, const float* __restrict__ Wy_w,
    float* __restrict__ zd, float* __restrict__ M,
    unsigned short* __restrict__ Wcat)
{
    int blk = blockIdx.x;
    int lane = threadIdx.x;

    if (blk < 2 * KK * CC) {
        bool isM = (blk >= KK * CC);
        int e2 = isM ? blk - KK * CC : blk;
        int k = e2 / CC, c = e2 % CC;
        const float4* a4 = reinterpret_cast<const float4*>(dic + (size_t)k * DD);
        const float*  w  = isM ? (cs_w + (size_t)c * (2 * DD) + DD) : (Wz_w + (size_t)c * DD);
        const float4* w4 = reinterpret_cast<const float4*>(w);
        float p = 0.f;
        #pragma unroll
        for (int i = 0; i < 4; ++i) {
            float4 av = a4[lane + 64 * i];
            float4 wv = w4[lane + 64 * i];
            p += DOT4(av, wv);
        }
        p = wave_reduce_sum(p);
        if (lane == 0) {
            if (isM) M[e2] = p;
            else     zd[e2] = p + Wz_b[c];
        }
    } else {
        int e2 = blk - 2 * KK * CC;       // 0..23, each converts 2048 elems
        int base = e2 * 2048;
        #pragma unroll
        for (int t = 0; t < 32; ++t) {
            int i = base + lane + 64 * t;
            int c = i >> 10, k = i & 1023;
            float v;
            if (c < CC)          v = Wy_w[(size_t)c * DD + k];
            else if (c < 2 * CC) v = cs_w[(size_t)(c - CC) * (2 * DD) + k];
            else                 v = 0.f;
            Wcat[i] = f2bf(v);
        }
    }
}

// ---------------------------------------------------------------------------
// Kernel 1 v8 (MFMA, 8-row blocks for multi-block/CU overlap):
//   512 blocks x 256 thr (4 waves). Block owns 8 x-rows; LDS ~26 KB ->
//   4+ blocks/CU co-resident (the R15 diagnosis: 1 block/CU = pure stall).
//   Stage: 8 rows f32 -> bf16 xT (VGPR path, coalesced; 256 float4/row).
//   Wave w: K-slice [256w,256w+256), 8 ks-steps x 3 MFMA (A rows 8..15
//   duplicate rows 0..7; D rows 8..15 are duplicates, dropped).
//   pacc[4][8][49] reduce -> wave-0 epilogue (verified softmax + lz).
// ---------------------------------------------------------------------------
__global__ __launch_bounds__(256) void k1_mfma(
    const float* __restrict__ x,
    const float* __restrict__ prior,
    const float* __restrict__ Wy_b, const float* __restrict__ cs_b,
    const unsigned short* __restrict__ Wcat,
    const float* __restrict__ zd, const float* __restrict__ M,
    float* __restrict__ ly_ws, float* __restrict__ lz_ws)
{
    const int tid  = threadIdx.x;
    const int wid  = tid >> 6;          // 0..3
    const int lane = tid & 63;
    const int fr   = lane & 15;
    const int frm  = fr & 7;            // A-row (rows 8..15 duplicate 0..7)
    const int kg   = lane >> 4;
    const int r0   = blockIdx.x * 8;

    __shared__ float zds[KK * CC];
    __shared__ float Ms[KK * CC];
    __shared__ float pr[KK];
    __shared__ float bias[2 * CC];          // [0..20]=Wy_b, [21..41]=cs_b
    __shared__ unsigned short xT[8 * XS];   // 16.5 KB bf16
    __shared__ float pacc[4 * 8 * 49];      // 6.3 KB

    for (int i = tid; i < KK * CC; i += 256) { zds[i] = zd[i]; Ms[i] = M[i]; }
    if (tid < KK) pr[tid] = prior[tid];
    if (tid < CC) { bias[tid] = Wy_b[tid]; bias[CC + tid] = cs_b[tid]; }

    // ---- stage 8 rows f32 -> bf16, coalesced: 2048 float4, 256/row ----
    #pragma unroll
    for (int i = 0; i < 8; ++i) {
        int f = tid + i * 256;          // 0..2047
        int row  = f >> 8;              // 256 float4 per row -> row 0..7
        int col4 = f & 255;
        float4 v = *reinterpret_cast<const float4*>(x + (size_t)(r0 + row) * DD + col4 * 4);
        unsigned int lo = (unsigned int)f2bf(v.x) | ((unsigned int)f2bf(v.y) << 16);
        unsigned int hi = (unsigned int)f2bf(v.z) | ((unsigned int)f2bf(v.w) << 16);
        *reinterpret_cast<uint2*>(&xT[row * XS + col4 * 4]) = make_uint2(lo, hi);
    }
    __syncthreads();

    // ---- MFMA over this wave's K-slice ----
    const int kbase = wid * 256;
    const unsigned short* w0p = Wcat + (size_t)(fr +  0) * DD + kbase + kg * 8;
    const unsigned short* w1p = Wcat + (size_t)(fr + 16) * DD + kbase + kg * 8;
    const unsigned short* w2p = Wcat + (size_t)(fr + 32) * DD + kbase + kg * 8;
    const unsigned short* ap  = &xT[frm * XS + kbase + kg * 8];

    f32x4 acc0 = {0.f, 0.f, 0.f, 0.f};
    f32x4 acc1 = {0.f, 0.f, 0.f, 0.f};
    f32x4 acc2 = {0.f, 0.f, 0.f, 0.f};

    #pragma unroll
    for (int ks = 0; ks < 8; ++ks) {
        bf16x8 af = *reinterpret_cast<const bf16x8*>(ap + ks * 32);
        bf16x8 b0 = *reinterpret_cast<const bf16x8*>(w0p + ks * 32);
        bf16x8 b1 = *reinterpret_cast<const bf16x8*>(w1p + ks * 32);
        bf16x8 b2 = *reinterpret_cast<const bf16x8*>(w2p + ks * 32);
        acc0 = __builtin_amdgcn_mfma_f32_16x16x32_bf16(af, b0, acc0, 0, 0, 0);
        acc1 = __builtin_amdgcn_mfma_f32_16x16x32_bf16(af, b1, acc1, 0, 0, 0);
        acc2 = __builtin_amdgcn_mfma_f32_16x16x32_bf16(af, b2, acc2, 0, 0, 0);
    }

    // D frags -> pacc[wid]: m = kg*4+j; only m<8 valid (kg 0,1)
    if (kg < 2) {
        #pragma unroll
        for (int j = 0; j < 4; ++j) {
            float* pw = pacc + ((wid * 8) + kg * 4 + j) * 49;
            pw[fr]      = acc0[j];
            pw[16 + fr] = acc1[j];
            pw[32 + fr] = acc2[j];
        }
    }
    __syncthreads();

    // cross-wave reduce: 384 outputs, 4-way, thread-owned, in-place into w=0
    for (int o = tid; o < 384; o += 256) {
        int row = o / 48, col = o % 48;
        float s = pacc[row * 49 + col]
                + pacc[(8  + row) * 49 + col]
                + pacc[(16 + row) * 49 + col]
                + pacc[(24 + row) * 49 + col];
        pacc[row * 49 + col] = s;
    }
    __syncthreads();

    // wave-0 epilogue: row r = tid&7 (8-way redundant over g=tid>>3), lz c=g::8
    if (tid < 64) {
        const int r = tid & 7;
        const int g = tid >> 3;
        const float* f = pacc + r * 49;
        const float scale = 0.21821789023599238f;   // 1/sqrt(21)
        float s[KK];
        float m = -1e30f;
        #pragma unroll
        for (int k = 0; k < KK; ++k) {
            float t = 0.f;
            #pragma unroll
            for (int c = 0; c < CC; ++c) t += (f[c] + bias[c]) * zds[k * CC + c];
            s[k] = t * scale;
            m = fmaxf(m, s[k]);
        }
        float sum = 0.f;
        #pragma unroll
        for (int k = 0; k < KK; ++k) { s[k] = expf(s[k] - m); sum += s[k]; }
        float inv = 1.f / sum;
        float wk[KK];
        #pragma unroll
        for (int k = 0; k < KK; ++k) wk[k] = s[k] * inv * pr[k];

        size_t rr = (size_t)(r0 + r);
        for (int c = g; c < CC; c += 8) {
            float lzv = bias[CC + c];                   // cs_b
            #pragma unroll
            for (int k = 0; k < KK; ++k) lzv += wk[k] * Ms[k * CC + c];
            ly_ws[rr * CC + c] = f[CC + c];             // cols 21..41 = ly
            lz_ws[rr * CC + c] = lzv;
        }
    }
}

// ---------------------------------------------------------------------------
// Kernel 2: outer-sum write — measured 49.3 us at 7.15 TB/s (89% peak). Done.
// ---------------------------------------------------------------------------
__global__ __launch_bounds__(512) void k2_outer(
    const float* __restrict__ ly_ws, const float* __restrict__ lz_ws,
    float* __restrict__ out)
{
    int tid = threadIdx.x;
    int blk = blockIdx.x;               // 0..1023
    int b  = blk >> 8;                  // 256 blocks per image
    int i0 = (blk & 255) << 2;          // * 4 panels

    __shared__ vf4 lyp4[4 * CC];
    {
        float* lyp = reinterpret_cast<float*>(lyp4);
        if (tid < 4 * 84) {
            int i = tid / 84, f = tid % 84;
            lyp[i * 84 + f] = ly_ws[(size_t)(b * LL + i0 + i) * CC + (f % 21)];
        }
    }
    const float* lzp = lz_ws + (size_t)b * LC;
    vf4 lzv[11];
    #pragma unroll
    for (int it = 0; it < 11; ++it) {
        int idx = tid + it * 512;
        lzv[it] = (idx < NQ) ? *reinterpret_cast<const vf4*>(lzp + (size_t)idx * 4)
                             : (vf4){0.f, 0.f, 0.f, 0.f};
    }
    __syncthreads();
    int g0 = tid % 21;                  // (tid + it*512) % 21 steps by +8 mod 21

    #pragma unroll
    for (int i = 0; i < 4; ++i) {
        float* op = out + (size_t)(b * LL + i0 + i) * LC;
        const vf4* lyp_i = lyp4 + i * CC;
        int g = g0;
        #pragma unroll
        for (int it = 0; it < 11; ++it) {
            int idx = tid + it * 512;
            if (idx < NQ) {
                *reinterpret_cast<vf4*>(op + (size_t)idx * 4) = lzv[it] + lyp_i[g];
            }
            g += 8; if (g >= 21) g -= 21;
        }
    }
}

extern "C" void kernel_launch(void* const* d_in, const int* in_sizes, int n_in,
                              void* d_out, int out_size, void* d_ws, size_t ws_size,
                              hipStream_t stream)
{
    const float* x     = (const float*)d_in[0];
    const float* dic   = (const float*)d_in[1];
    const float* prior = (const float*)d_in[2];
    const float* Wy_w  = (const float*)d_in[3];
    const float* Wy_b  = (const float*)d_in[4];
    const float* Wz_w  = (const float*)d_in[5];
    const float* Wz_b  = (const float*)d_in[6];
    const float* cs_w  = (const float*)d_in[7];
    const float* cs_b  = (const float*)d_in[8];
    float* out = (float*)d_out;

    float* ws = (float*)d_ws;
    float* zd = ws;                       // 420 floats
    float* M  = ws + 512;                 // 420 floats
    float* ly = ws + 1024;                // B*L*C = 86016 floats
    float* lz = ly + BB * LL * CC;        // 86016 floats
    unsigned short* Wcat = (unsigned short*)(ws + 1024 + 2 * BB * LL * CC);  // 48*1024 bf16

    k0_zdM <<<dim3(2 * KK * CC + 24), dim3(64),  0, stream>>>(dic, Wz_w, Wz_b, cs_w, Wy_w,
                                                              zd, M, Wcat);
    k1_mfma<<<dim3(BB * LL / 8),      dim3(256), 0, stream>>>(x, prior, Wy_b, cs_b, Wcat,
                                                              zd, M, ly, lz);
    k2_outer<<<dim3(BB * LL / 4),     dim3(512), 0, stream>>>(ly, lz, out);
}